// Round 7
// baseline (354.784 us; speedup 1.0000x reference)
//
#include <hip/hip_runtime.h>

// YOLO head: input [B, 255, 80, 80] f32, anchors [3,2] f32
// output [B, 3*80*80, 85] f32.
// out[b, a*6400 + h*80 + w, c] = f(in[b, a*85 + c, h, w]) where
//   c==0: (sigmoid(x)+w)*8   c==1: (sigmoid(x)+h)*8
//   c==2: exp(clip(x,±16))*anchor_w[a]   c==3: exp(clip(x,±16))*anchor_h[a]
//   c>=4: sigmoid(x)
// Memory-bound transpose: stage per-(b,a,h) 80x85 tile in LDS in OUTPUT-LINEAR
// layout so the store phase is pure ds_read_b128 + global_store_dwordx4.
// R3 evidence: kernel device time < 126 us (absent from top-5; fills at 129 us
// dominate). R4: fast sigmoid (v_exp+v_rcp), full unroll, NT stores via
// native ext_vector float4 (HIP float4 class is rejected by the builtin).

#define NA 3
#define ATTRS 85
#define GH 80
#define GW 80
#define HW 6400            // GH*GW
#define CIN (NA * ATTRS)   // 255
#define STRIDE_PX 8.0f     // 640/80

constexpr int TILE_ELEMS = ATTRS * GW;       // 6800 floats per block tile
constexpr int TILE_F4    = TILE_ELEMS / 4;   // 1700

typedef float f32x4 __attribute__((ext_vector_type(4)));  // native vec for builtins

// Fast sigmoid: v_exp_f32 (2^x) + v_rcp_f32. rel err ~1e-7.
// Inputs are N(0,1); v_exp saturates gracefully for extremes anyway
// (exp2->inf => rcp(inf)=0 ; exp2->0 => rcp(1)=1).
__device__ __forceinline__ float sigmoid_fast(float x) {
    float e = __builtin_amdgcn_exp2f(-x * 1.44269504088896341f);
    return __builtin_amdgcn_rcpf(1.0f + e);
}

__global__ __launch_bounds__(256) void yolo_head_kernel(
    const float* __restrict__ in,
    const float* __restrict__ anchors,
    float* __restrict__ out)
{
    __shared__ float tile[TILE_ELEMS];   // [w][c] linear, 27200 B

    const int bid = blockIdx.x;
    const int h   = bid % GH;
    const int t2  = bid / GH;
    const int a   = t2 % NA;
    const int b   = t2 / NA;

    const float aw = anchors[2 * a + 0];
    const float ah = anchors[2 * a + 1];

    // input base for (b, a, channel 0, row h)
    const float* src = in + ((size_t)(b * CIN + a * ATTRS)) * HW + h * GW;

    // ---- load + transform: 1700 float4 coalesced reads ----
    #pragma unroll 7
    for (int li = threadIdx.x; li < TILE_F4; li += 256) {
        const int c = li / (GW / 4);        // channel 0..84
        const int v = li % (GW / 4);        // float4 index within row
        const f32x4 x4 =
            *reinterpret_cast<const f32x4*>(src + (size_t)c * HW + v * 4);
        #pragma unroll
        for (int j = 0; j < 4; ++j) {
            const int w = v * 4 + j;
            const float x = x4[j];
            float r;
            if (c == 0) {
                r = (sigmoid_fast(x) + (float)w) * STRIDE_PX;
            } else if (c == 1) {
                r = (sigmoid_fast(x) + (float)h) * STRIDE_PX;
            } else if (c == 2) {
                // keep accurate expf: values up to exp(16)*40 ~ 3.5e8,
                // fast-exp rel err would inflate absmax past the observed 0.25
                r = expf(fminf(fmaxf(x, -16.0f), 16.0f)) * aw;
            } else if (c == 3) {
                r = expf(fminf(fmaxf(x, -16.0f), 16.0f)) * ah;
            } else {
                r = sigmoid_fast(x);
            }
            tile[w * ATTRS + c] = r;        // output-linear scatter
        }
    }

    __syncthreads();

    // ---- store: 1700 float4 LDS b128 reads + coalesced NT global writes ----
    // block's output region: out[b, a*6400 + h*80 + (0..79), 0..84]
    f32x4* dst = reinterpret_cast<f32x4*>(
        out + (size_t)((b * NA + a) * HW + h * GW) * ATTRS);
    const f32x4* tsrc = reinterpret_cast<const f32x4*>(tile);
    #pragma unroll 7
    for (int oi = threadIdx.x; oi < TILE_F4; oi += 256) {
        __builtin_nontemporal_store(tsrc[oi], &dst[oi]);
    }
}

extern "C" void kernel_launch(void* const* d_in, const int* in_sizes, int n_in,
                              void* d_out, int out_size, void* d_ws, size_t ws_size,
                              hipStream_t stream) {
    const float* in      = (const float*)d_in[0];
    const float* anchors = (const float*)d_in[1];
    float* out           = (float*)d_out;

    const int B = in_sizes[0] / (CIN * HW);   // 32
    const int grid = B * NA * GH;             // 7680 blocks

    yolo_head_kernel<<<grid, 256, 0, stream>>>(in, anchors, out);
}